// Round 3
// baseline (362.293 us; speedup 1.0000x reference)
//
#include <hip/hip_runtime.h>
#include <math.h>

#define NN 10000
#define NE 256000
#define HD 128
#define PD 64
#define NBASIS 8
#define NSPEC 10
#define RHID 64
#define RCUT 5.0f
#define INV_AVG 0.0390625f   // 1/25.6 exact
#define PI_F 3.14159265358979f

__device__ __forceinline__ float silu(float x) {
    return x / (1.0f + expf(-x));
}

// ---------------- zero accumulators + counters ----------------
__global__ void k_zero(float4* acc, int* cnt, int* hist, long n4) {
    long i = (long)blockIdx.x * blockDim.x + threadIdx.x;
    if (i == 0) {
        *cnt = 0;
        for (int s = 0; s < NSPEC; s++) hist[s] = 0;
    }
    long stride = (long)gridDim.x * blockDim.x;
    float4 z = make_float4(0.f, 0.f, 0.f, 0.f);
    for (; i < n4; i += stride) acc[i] = z;
}

// ---------------- species id per node + histogram ----------------
__global__ void k_species(const float* __restrict__ na, int* __restrict__ spec, int* hist) {
    int n = blockIdx.x * 256 + threadIdx.x;
    if (n >= NN) return;
    int s = 0;
    for (int k = 0; k < NSPEC; k++)
        if (na[n * NSPEC + k] > 0.5f) s = k;
    spec[n] = s;
    atomicAdd(&hist[s], 1);
}

// ---------------- tiny exclusive scan over 10 species ----------------
__global__ void k_scan(const int* __restrict__ hist, int* __restrict__ basep) {
    if (threadIdx.x == 0) {
        int acc = 0;
        for (int s = 0; s < NSPEC; s++) { basep[s] = acc; acc += hist[s]; }
    }
}

// ---------------- scatter node ids into species-sorted order ----------------
__global__ void k_scatter(const int* __restrict__ spec, int* basep, int* __restrict__ ord) {
    int n = blockIdx.x * 256 + threadIdx.x;
    if (n >= NN) return;
    int pos = atomicAdd(&basep[spec[n]], 1);
    ord[pos] = n;
}

// ---------------- per-species tables: sc0_s, h0_s ----------------
__global__ void k_tables(const float* __restrict__ We, const float* __restrict__ Wsc1,
                         const float* __restrict__ Wup01,
                         float* __restrict__ sc0s, float* __restrict__ h0s) {
    int t = blockIdx.x * 256 + threadIdx.x;
    if (t >= NSPEC * HD) return;
    int s = t / HD, h = t % HD;
    float acc1 = 0.f, acc2 = 0.f;
    for (int c = 0; c < HD; c++) {
        float fe = We[s * HD + c];
        acc1 += fe * Wsc1[(s * HD + c) * HD + h];
        acc2 += fe * Wup01[c * HD + h];
    }
    sc0s[t] = acc1;
    h0s[t] = acc2;
}

// ---------------- edge compaction: geometry + radial basis ----------------
__global__ void k_compact(const float* __restrict__ pos, const float* __restrict__ shifts,
                          const int* __restrict__ ii, const int* __restrict__ jj,
                          int* cnt, int* __restrict__ ai, int* __restrict__ aj,
                          float* __restrict__ aY, float* __restrict__ aF) {
    int e = blockIdx.x * 256 + threadIdx.x;
    if (e >= NE) return;
    int i = ii[e], j = jj[e];
    float vx = pos[i * 3 + 0] - pos[j * 3 + 0] - shifts[e * 3 + 0];
    float vy = pos[i * 3 + 1] - pos[j * 3 + 1] - shifts[e * 3 + 1];
    float vz = pos[i * 3 + 2] - pos[j * 3 + 2] - shifts[e * 3 + 2];
    float r = sqrtf(vx * vx + vy * vy + vz * vz);
    r = fmaxf(r, 1e-9f);
    if (r >= RCUT) return;   // env==0 exactly -> message exactly 0 -> skip
    int slot = atomicAdd(cnt, 1);
    ai[slot] = i; aj[slot] = j;
    float inv = 1.0f / r;
    aY[slot * 3 + 0] = vx * inv;
    aY[slot * 3 + 1] = vy * inv;
    aY[slot * 3 + 2] = vz * inv;
    float u = r * (1.0f / RCUT);
    float u5 = u * u * u * u * u;
    float env = 1.0f - 21.0f * u5 + 35.0f * u5 * u - 15.0f * u5 * u * u;
    float c0 = 0.6324555320336759f * env * inv;  // sqrt(2/RC)
    for (int b = 1; b <= NBASIS; b++)
        aF[slot * NBASIS + b - 1] = c0 * sinf((float)b * PI_F * r * (1.0f / RCUT));
}

// ---------------- layer-1 edge: 4 edges per wave, gathers hoisted ----------------
__global__ __launch_bounds__(256) void k_edge1(
    const int* __restrict__ cnt, const int* __restrict__ ai, const int* __restrict__ aj,
    const float* __restrict__ aY, const float* __restrict__ aF, const int* __restrict__ spec,
    const float* __restrict__ R0, const float* __restrict__ R1,
    const float* __restrict__ R2, const float* __restrict__ R3,
    const float* __restrict__ h0s, float* __restrict__ a0, float* __restrict__ a1) {
    int lane = threadIdx.x & 63;
    int wid = (blockIdx.x * blockDim.x + threadIdx.x) >> 6;
    int nw = (gridDim.x * blockDim.x) >> 6;
    int nact = *cnt;
    for (int base = wid * 4; base < nact; base += nw * 4) {
        int ne = nact - base; if (ne > 4) ne = 4;
        // ---- hoisted per-edge meta (lane-uniform -> SGPR) + per-lane gathers ----
        int ei[4], ej[4];
        float Y[4][3], F[4][NBASIS];
        float h0a[4], h0b[4];
        #pragma unroll
        for (int k = 0; k < 4; k++) {
            int ee = base + ((k < ne) ? k : 0);
            ei[k] = ai[ee]; ej[k] = aj[ee];
            #pragma unroll
            for (int d = 0; d < 3; d++) Y[k][d] = aY[ee * 3 + d];
            #pragma unroll
            for (int b = 0; b < NBASIS; b++) F[k][b] = aF[ee * NBASIS + b];
        }
        #pragma unroll
        for (int k = 0; k < 4; k++) {
            const float* h0 = h0s + spec[ej[k]] * HD;
            h0a[k] = h0[lane]; h0b[k] = h0[64 + lane];
        }
        // ---- radial MLP (compute covers gather latency) ----
        float x[4];
        #pragma unroll
        for (int k = 0; k < 4; k++) {
            float acc = 0.f;
            #pragma unroll
            for (int b = 0; b < NBASIS; b++) acc += F[k][b] * R0[b * RHID + lane];
            x[k] = silu(acc);
        }
        {
            float acc[4] = {0.f, 0.f, 0.f, 0.f};
            for (int c = 0; c < RHID; c++) {
                float wv = R1[c * RHID + lane];
                #pragma unroll
                for (int k = 0; k < 4; k++) acc[k] += __shfl(x[k], c) * wv;
            }
            #pragma unroll
            for (int k = 0; k < 4; k++) x[k] = silu(acc[k]);
        }
        {
            float acc[4] = {0.f, 0.f, 0.f, 0.f};
            for (int c = 0; c < RHID; c++) {
                float wv = R2[c * RHID + lane];
                #pragma unroll
                for (int k = 0; k < 4; k++) acc[k] += __shfl(x[k], c) * wv;
            }
            #pragma unroll
            for (int k = 0; k < 4; k++) x[k] = silu(acc[k]);
        }
        float w00[4] = {0,0,0,0}, w01[4] = {0,0,0,0}, w10[4] = {0,0,0,0}, w11[4] = {0,0,0,0};
        for (int c = 0; c < RHID; c++) {
            const float* row = R3 + c * (2 * HD);
            float l0 = row[lane], l1 = row[64 + lane], l2 = row[128 + lane], l3 = row[192 + lane];
            #pragma unroll
            for (int k = 0; k < 4; k++) {
                float xc = __shfl(x[k], c);
                w00[k] += xc * l0; w01[k] += xc * l1; w10[k] += xc * l2; w11[k] += xc * l3;
            }
        }
        // ---- scatter (planar a1: [3][NN][HD]) ----
        #pragma unroll
        for (int k = 0; k < 4; k++) {
            if (k >= ne) break;
            int i = ei[k];
            float m0a = w00[k] * h0a[k] * INV_AVG, m0b = w01[k] * h0b[k] * INV_AVG;
            float m1a = w10[k] * h0a[k] * INV_AVG, m1b = w11[k] * h0b[k] * INV_AVG;
            atomicAdd(&a0[(size_t)i * HD + lane], m0a);
            atomicAdd(&a0[(size_t)i * HD + 64 + lane], m0b);
            #pragma unroll
            for (int d = 0; d < 3; d++) {
                atomicAdd(&a1[((size_t)d * NN + i) * HD + lane], m1a * Y[k][d]);
                atomicAdd(&a1[((size_t)d * NN + i) * HD + 64 + lane], m1b * Y[k][d]);
            }
        }
    }
}

// ---------------- fused nodeA+nodeB: 16 nodes/block, 4/wave, wave-private ----------------
__global__ __launch_bounds__(256) void k_nodeAB(
    const float* __restrict__ a0, const float* __restrict__ a1,
    const int* __restrict__ ord, const int* __restrict__ spec,
    const float* __restrict__ Wout0, const float* __restrict__ Wout1,
    const float* __restrict__ Wp0, const float* __restrict__ Wp1,
    const float* __restrict__ Wl0, const float* __restrict__ Wl1,
    const float* __restrict__ sc0s,
    const float* __restrict__ Wsc2, const float* __restrict__ Wup02, const float* __restrict__ Wup12,
    float* __restrict__ out0, float* __restrict__ sc0b,
    float* __restrict__ g0, float* __restrict__ g1) {
    __shared__ float sIn0[16][HD];        // a0 rows -> later out0 rows
    __shared__ float sIn1[3][16][HD];     // a1 planes -> later out1 planes
    int lane = threadIdx.x & 63, w = threadIdx.x >> 6, w4 = w * 4;
    int nb = blockIdx.x * 16;
    int n[4], sk[4];
    #pragma unroll
    for (int k = 0; k < 4; k++) { n[k] = ord[nb + w4 + k]; sk[k] = spec[n[k]]; }
    // wave-private staging (no barriers anywhere in this kernel)
    #pragma unroll
    for (int k = 0; k < 4; k++) {
        const float* s0 = a0 + (size_t)n[k] * HD;
        for (int t = lane; t < HD; t += 64) sIn0[w4 + k][t] = s0[t];
        #pragma unroll
        for (int d = 0; d < 3; d++) {
            const float* s1 = a1 + ((size_t)d * NN + n[k]) * HD;
            for (int t = lane; t < HD; t += 64) sIn1[d][w4 + k][t] = s1[t];
        }
    }
    // phase A: A0/A1 (p = lane)
    float A0[4] = {0,0,0,0}, A1x[4] = {0,0,0,0}, A1y[4] = {0,0,0,0}, A1z[4] = {0,0,0,0};
    #pragma unroll 4
    for (int h = 0; h < HD; h++) {
        float w0 = Wout0[h * PD + lane], w1 = Wout1[h * PD + lane];
        #pragma unroll
        for (int k = 0; k < 4; k++) {
            A0[k] += sIn0[w4 + k][h] * w0;
            A1x[k] += sIn1[0][w4 + k][h] * w1;
            A1y[k] += sIn1[1][w4 + k][h] * w1;
            A1z[k] += sIn1[2][w4 + k][h] * w1;
        }
    }
    float B0k[4], B1k[4][3];
    #pragma unroll
    for (int k = 0; k < 4; k++) {
        int s = sk[k];
        float dot = A1x[k] * A1x[k] + A1y[k] * A1y[k] + A1z[k] * A1z[k];
        const float* wp0 = Wp0 + (s * 5) * PD;
        float A02 = A0[k] * A0[k];
        B0k[k] = wp0[lane] * A0[k] + wp0[PD + lane] * A02 + wp0[2 * PD + lane] * A02 * A0[k] +
                 wp0[3 * PD + lane] * dot + wp0[4 * PD + lane] * A0[k] * dot;
        const float* wp1 = Wp1 + (s * 4) * PD;
        float fac = wp1[lane] + wp1[PD + lane] * A0[k] + wp1[2 * PD + lane] * A02 + wp1[3 * PD + lane] * dot;
        B1k[k][0] = fac * A1x[k]; B1k[k][1] = fac * A1y[k]; B1k[k][2] = fac * A1z[k];
    }
    // phase B: out0/out1 via shuffle exchange over q
    float o0a[4] = {0,0,0,0}, o0b[4] = {0,0,0,0};
    float o1a[4][3] = {{0}}, o1b[4][3] = {{0}};
    for (int q = 0; q < PD; q++) {
        float wla = Wl0[q * HD + lane], wlb = Wl0[q * HD + 64 + lane];
        float wma = Wl1[q * HD + lane], wmb = Wl1[q * HD + 64 + lane];
        #pragma unroll
        for (int k = 0; k < 4; k++) {
            float b0 = __shfl(B0k[k], q);
            o0a[k] += b0 * wla; o0b[k] += b0 * wlb;
            #pragma unroll
            for (int d = 0; d < 3; d++) {
                float b1 = __shfl(B1k[k][d], q);
                o1a[k][d] += b1 * wma; o1b[k][d] += b1 * wmb;
            }
        }
    }
    // finalize out0 (+species shortcut), write global + LDS for phase C
    #pragma unroll
    for (int k = 0; k < 4; k++) {
        float va = o0a[k] + sc0s[sk[k] * HD + lane];
        float vb = o0b[k] + sc0s[sk[k] * HD + 64 + lane];
        out0[(size_t)n[k] * HD + lane] = va;
        out0[(size_t)n[k] * HD + 64 + lane] = vb;
        sIn0[w4 + k][lane] = va; sIn0[w4 + k][64 + lane] = vb;
        #pragma unroll
        for (int d = 0; d < 3; d++) {
            sIn1[d][w4 + k][lane] = o1a[k][d];
            sIn1[d][w4 + k][64 + lane] = o1b[k][d];
        }
    }
    // phase C: nodeB contractions over c
    bool uni = (sk[0] == sk[1]) && (sk[1] == sk[2]) && (sk[2] == sk[3]);
    float sba[4] = {0,0,0,0}, sbb[4] = {0,0,0,0}, ga[4] = {0,0,0,0}, gb[4] = {0,0,0,0};
    float g1a[4][3] = {{0}}, g1b[4][3] = {{0}};
    if (uni) {
        const float* Ws = Wsc2 + (size_t)sk[0] * HD * HD;
        #pragma unroll 2
        for (int c = 0; c < HD; c++) {
            float wsa = Ws[c * HD + lane], wsb = Ws[c * HD + 64 + lane];
            float wu0a = Wup02[c * HD + lane], wu0b = Wup02[c * HD + 64 + lane];
            float wu1a = Wup12[c * HD + lane], wu1b = Wup12[c * HD + 64 + lane];
            #pragma unroll
            for (int k = 0; k < 4; k++) {
                float v0 = sIn0[w4 + k][c];
                sba[k] += v0 * wsa; sbb[k] += v0 * wsb;
                ga[k] += v0 * wu0a; gb[k] += v0 * wu0b;
                float v1x = sIn1[0][w4 + k][c], v1y = sIn1[1][w4 + k][c], v1z = sIn1[2][w4 + k][c];
                g1a[k][0] += v1x * wu1a; g1a[k][1] += v1y * wu1a; g1a[k][2] += v1z * wu1a;
                g1b[k][0] += v1x * wu1b; g1b[k][1] += v1y * wu1b; g1b[k][2] += v1z * wu1b;
            }
        }
    } else {
        for (int c = 0; c < HD; c++) {
            float wu0a = Wup02[c * HD + lane], wu0b = Wup02[c * HD + 64 + lane];
            float wu1a = Wup12[c * HD + lane], wu1b = Wup12[c * HD + 64 + lane];
            #pragma unroll
            for (int k = 0; k < 4; k++) {
                const float* Ws = Wsc2 + (size_t)sk[k] * HD * HD;
                float wsa = Ws[c * HD + lane], wsb = Ws[c * HD + 64 + lane];
                float v0 = sIn0[w4 + k][c];
                sba[k] += v0 * wsa; sbb[k] += v0 * wsb;
                ga[k] += v0 * wu0a; gb[k] += v0 * wu0b;
                float v1x = sIn1[0][w4 + k][c], v1y = sIn1[1][w4 + k][c], v1z = sIn1[2][w4 + k][c];
                g1a[k][0] += v1x * wu1a; g1a[k][1] += v1y * wu1a; g1a[k][2] += v1z * wu1a;
                g1b[k][0] += v1x * wu1b; g1b[k][1] += v1y * wu1b; g1b[k][2] += v1z * wu1b;
            }
        }
    }
    #pragma unroll
    for (int k = 0; k < 4; k++) {
        int nn = n[k];
        sc0b[(size_t)nn * HD + lane] = sba[k];
        sc0b[(size_t)nn * HD + 64 + lane] = sbb[k];
        g0[(size_t)nn * HD + lane] = ga[k];
        g0[(size_t)nn * HD + 64 + lane] = gb[k];
        #pragma unroll
        for (int d = 0; d < 3; d++) {
            g1[((size_t)d * NN + nn) * HD + lane] = g1a[k][d];
            g1[((size_t)d * NN + nn) * HD + 64 + lane] = g1b[k][d];
        }
    }
}

// ---------------- layer-2 edge: 4 edges per wave, gathers hoisted, planar ----------------
__global__ __launch_bounds__(256) void k_edge2(
    const int* __restrict__ cnt, const int* __restrict__ ai, const int* __restrict__ aj,
    const float* __restrict__ aY, const float* __restrict__ aF,
    const float* __restrict__ R0, const float* __restrict__ R1,
    const float* __restrict__ R2, const float* __restrict__ R3,
    const float* __restrict__ g0, const float* __restrict__ g1,
    float* __restrict__ a0, float* __restrict__ a1) {
    int lane = threadIdx.x & 63;
    int wid = (blockIdx.x * blockDim.x + threadIdx.x) >> 6;
    int nw = (gridDim.x * blockDim.x) >> 6;
    int nact = *cnt;
    for (int base = wid * 4; base < nact; base += nw * 4) {
        int ne = nact - base; if (ne > 4) ne = 4;
        // ---- hoisted meta + gathers ----
        int ei[4], ej[4];
        float Y[4][3], F[4][NBASIS];
        float gva[4], gvb[4], g1av[4][3], g1bv[4][3];
        #pragma unroll
        for (int k = 0; k < 4; k++) {
            int ee = base + ((k < ne) ? k : 0);
            ei[k] = ai[ee]; ej[k] = aj[ee];
            #pragma unroll
            for (int d = 0; d < 3; d++) Y[k][d] = aY[ee * 3 + d];
            #pragma unroll
            for (int b = 0; b < NBASIS; b++) F[k][b] = aF[ee * NBASIS + b];
        }
        #pragma unroll
        for (int k = 0; k < 4; k++) {
            int j = ej[k];
            gva[k] = g0[(size_t)j * HD + lane];
            gvb[k] = g0[(size_t)j * HD + 64 + lane];
            #pragma unroll
            for (int d = 0; d < 3; d++) {
                g1av[k][d] = g1[((size_t)d * NN + j) * HD + lane];
                g1bv[k][d] = g1[((size_t)d * NN + j) * HD + 64 + lane];
            }
        }
        // ---- radial MLP ----
        float x[4];
        #pragma unroll
        for (int k = 0; k < 4; k++) {
            float acc = 0.f;
            #pragma unroll
            for (int b = 0; b < NBASIS; b++) acc += F[k][b] * R0[b * RHID + lane];
            x[k] = silu(acc);
        }
        {
            float acc[4] = {0.f, 0.f, 0.f, 0.f};
            for (int c = 0; c < RHID; c++) {
                float wv = R1[c * RHID + lane];
                #pragma unroll
                for (int k = 0; k < 4; k++) acc[k] += __shfl(x[k], c) * wv;
            }
            #pragma unroll
            for (int k = 0; k < 4; k++) x[k] = silu(acc[k]);
        }
        {
            float acc[4] = {0.f, 0.f, 0.f, 0.f};
            for (int c = 0; c < RHID; c++) {
                float wv = R2[c * RHID + lane];
                #pragma unroll
                for (int k = 0; k < 4; k++) acc[k] += __shfl(x[k], c) * wv;
            }
            #pragma unroll
            for (int k = 0; k < 4; k++) x[k] = silu(acc[k]);
        }
        float wa[4][5] = {{0}}, wb[4][5] = {{0}};
        for (int c = 0; c < RHID; c++) {
            const float* row = R3 + c * (5 * HD);
            float la[5], lb[5];
            #pragma unroll
            for (int q = 0; q < 5; q++) { la[q] = row[q * HD + lane]; lb[q] = row[q * HD + 64 + lane]; }
            #pragma unroll
            for (int k = 0; k < 4; k++) {
                float xc = __shfl(x[k], c);
                #pragma unroll
                for (int q = 0; q < 5; q++) { wa[k][q] += xc * la[q]; wb[k][q] += xc * lb[q]; }
            }
        }
        // ---- combine + scatter ----
        #pragma unroll
        for (int k = 0; k < 4; k++) {
            if (k >= ne) break;
            int i = ei[k];
            float Yx = Y[k][0], Yy = Y[k][1], Yz = Y[k][2];
            float gax = g1av[k][0], gay = g1av[k][1], gaz = g1av[k][2];
            float gbx = g1bv[k][0], gby = g1bv[k][1], gbz = g1bv[k][2];
            float dota = gax * Yx + gay * Yy + gaz * Yz;
            float dotb = gbx * Yx + gby * Yy + gbz * Yz;
            float m0a = (wa[k][0] * gva[k] + wa[k][3] * dota) * INV_AVG;
            float m0b = (wb[k][0] * gvb[k] + wb[k][3] * dotb) * INV_AVG;
            float cax = gay * Yz - gaz * Yy, cay = gaz * Yx - gax * Yz, caz = gax * Yy - gay * Yx;
            float cbx = gby * Yz - gbz * Yy, cby = gbz * Yx - gbx * Yz, cbz = gbx * Yy - gby * Yx;
            float m1a[3], m1b[3];
            m1a[0] = (wa[k][1] * gva[k] * Yx + wa[k][2] * gax + wa[k][4] * cax) * INV_AVG;
            m1a[1] = (wa[k][1] * gva[k] * Yy + wa[k][2] * gay + wa[k][4] * cay) * INV_AVG;
            m1a[2] = (wa[k][1] * gva[k] * Yz + wa[k][2] * gaz + wa[k][4] * caz) * INV_AVG;
            m1b[0] = (wb[k][1] * gvb[k] * Yx + wb[k][2] * gbx + wb[k][4] * cbx) * INV_AVG;
            m1b[1] = (wb[k][1] * gvb[k] * Yy + wb[k][2] * gby + wb[k][4] * cby) * INV_AVG;
            m1b[2] = (wb[k][1] * gvb[k] * Yz + wb[k][2] * gbz + wb[k][4] * cbz) * INV_AVG;
            atomicAdd(&a0[(size_t)i * HD + lane], m0a);
            atomicAdd(&a0[(size_t)i * HD + 64 + lane], m0b);
            #pragma unroll
            for (int d = 0; d < 3; d++) {
                atomicAdd(&a1[((size_t)d * NN + i) * HD + lane], m1a[d]);
                atomicAdd(&a1[((size_t)d * NN + i) * HD + 64 + lane], m1b[d]);
            }
        }
    }
}

// ---------------- nodeC: 16 nodes/block, 4/wave, wave-private, planar ----------------
__global__ __launch_bounds__(256) void k_nodeC(
    const float* __restrict__ a0, const float* __restrict__ a1, const int* __restrict__ spec,
    const float* __restrict__ Wout0, const float* __restrict__ Wout1,
    const float* __restrict__ Wp0, const float* __restrict__ Wl0,
    const float* __restrict__ sc0b, float* __restrict__ outb) {
    __shared__ float sIn0[16][HD];
    __shared__ float sIn1[3][16][HD];
    int lane = threadIdx.x & 63, w = threadIdx.x >> 6, w4 = w * 4;
    int nb = blockIdx.x * 16;
    #pragma unroll
    for (int k = 0; k < 4; k++) {
        int nn = nb + w4 + k;
        const float* s0 = a0 + (size_t)nn * HD;
        for (int t = lane; t < HD; t += 64) sIn0[w4 + k][t] = s0[t];
        #pragma unroll
        for (int d = 0; d < 3; d++) {
            const float* s1 = a1 + ((size_t)d * NN + nn) * HD;
            for (int t = lane; t < HD; t += 64) sIn1[d][w4 + k][t] = s1[t];
        }
    }
    float A0[4] = {0,0,0,0}, A1x[4] = {0,0,0,0}, A1y[4] = {0,0,0,0}, A1z[4] = {0,0,0,0};
    #pragma unroll 4
    for (int h = 0; h < HD; h++) {
        float w0 = Wout0[h * PD + lane], w1 = Wout1[h * PD + lane];
        #pragma unroll
        for (int k = 0; k < 4; k++) {
            A0[k] += sIn0[w4 + k][h] * w0;
            A1x[k] += sIn1[0][w4 + k][h] * w1;
            A1y[k] += sIn1[1][w4 + k][h] * w1;
            A1z[k] += sIn1[2][w4 + k][h] * w1;
        }
    }
    float B0k[4];
    #pragma unroll
    for (int k = 0; k < 4; k++) {
        int s = spec[nb + w4 + k];
        float dot = A1x[k] * A1x[k] + A1y[k] * A1y[k] + A1z[k] * A1z[k];
        const float* wp0 = Wp0 + (s * 5) * PD;
        float A02 = A0[k] * A0[k];
        B0k[k] = wp0[lane] * A0[k] + wp0[PD + lane] * A02 + wp0[2 * PD + lane] * A02 * A0[k] +
                 wp0[3 * PD + lane] * dot + wp0[4 * PD + lane] * A0[k] * dot;
    }
    float oa[4] = {0,0,0,0}, ob[4] = {0,0,0,0};
    for (int q = 0; q < PD; q++) {
        float wla = Wl0[q * HD + lane], wlb = Wl0[q * HD + 64 + lane];
        #pragma unroll
        for (int k = 0; k < 4; k++) {
            float b0 = __shfl(B0k[k], q);
            oa[k] += b0 * wla; ob[k] += b0 * wlb;
        }
    }
    #pragma unroll
    for (int k = 0; k < 4; k++) {
        int nn = nb + w4 + k;
        outb[(size_t)nn * HD + lane] = oa[k] + sc0b[(size_t)nn * HD + lane];
        outb[(size_t)nn * HD + 64 + lane] = ob[k] + sc0b[(size_t)nn * HD + 64 + lane];
    }
}

extern "C" void kernel_launch(void* const* d_in, const int* in_sizes, int n_in,
                              void* d_out, int out_size, void* d_ws, size_t ws_size,
                              hipStream_t stream) {
    const float* pos    = (const float*)d_in[0];
    const float* shifts = (const float*)d_in[1];
    const float* na     = (const float*)d_in[2];
    const float* We     = (const float*)d_in[3];
    const float* Wsc1   = (const float*)d_in[4];
    const float* Wup01  = (const float*)d_in[5];
    const float* R10    = (const float*)d_in[6];
    const float* R11    = (const float*)d_in[7];
    const float* R12    = (const float*)d_in[8];
    const float* R13    = (const float*)d_in[9];
    const float* Wout01 = (const float*)d_in[10];
    const float* Wout11 = (const float*)d_in[11];
    const float* Wp01   = (const float*)d_in[12];
    const float* Wp11   = (const float*)d_in[13];
    const float* Wl01   = (const float*)d_in[14];
    const float* Wl11   = (const float*)d_in[15];
    const float* Wsc2   = (const float*)d_in[16];
    const float* Wup02  = (const float*)d_in[17];
    const float* Wup12  = (const float*)d_in[18];
    const float* R20    = (const float*)d_in[19];
    const float* R21    = (const float*)d_in[20];
    const float* R22    = (const float*)d_in[21];
    const float* R23    = (const float*)d_in[22];
    const float* Wout02 = (const float*)d_in[23];
    const float* Wout12 = (const float*)d_in[24];
    const float* Wp02   = (const float*)d_in[25];
    const float* Wl02   = (const float*)d_in[26];
    const int*   idx_i  = (const int*)d_in[27];
    const int*   idx_j  = (const int*)d_in[28];
    float* out = (float*)d_out;

    char* ws = (char*)d_ws;
    size_t off = 0;
    auto alloc = [&](size_t bytes) -> char* {
        char* pp = ws + off;
        off += (bytes + 255) & ~(size_t)255;
        return pp;
    };
    int*   cnt   = (int*)alloc(4);
    int*   hist  = (int*)alloc(NSPEC * 4);
    int*   basep = (int*)alloc(NSPEC * 4);
    // the next 4 arrays must stay contiguous for k_zero (8*NN*HD floats total)
    float* a0_1  = (float*)alloc((size_t)NN * HD * 4);
    float* a1_1  = (float*)alloc((size_t)NN * HD * 3 * 4);   // planar [3][NN][HD]
    float* a0_2  = (float*)alloc((size_t)NN * HD * 4);
    float* a1_2  = (float*)alloc((size_t)NN * HD * 3 * 4);   // planar
    int*   act_i = (int*)alloc((size_t)NE * 4);
    int*   act_j = (int*)alloc((size_t)NE * 4);
    float* actY  = (float*)alloc((size_t)NE * 3 * 4);
    float* actF  = (float*)alloc((size_t)NE * NBASIS * 4);
    int*   spec  = (int*)alloc((size_t)NN * 4);
    int*   ordn  = (int*)alloc((size_t)NN * 4);
    float* sc0s  = (float*)alloc((size_t)NSPEC * HD * 4);
    float* h0s   = (float*)alloc((size_t)NSPEC * HD * 4);
    float* sc0b  = (float*)alloc((size_t)NN * HD * 4);
    float* g0    = (float*)alloc((size_t)NN * HD * 4);
    float* g1    = (float*)alloc((size_t)NN * HD * 3 * 4);   // planar

    long n4 = (long)NN * HD * 8 / 4;
    k_zero<<<2048, 256, 0, stream>>>((float4*)a0_1, cnt, hist, n4);
    k_species<<<(NN + 255) / 256, 256, 0, stream>>>(na, spec, hist);
    k_scan<<<1, 64, 0, stream>>>(hist, basep);
    k_scatter<<<(NN + 255) / 256, 256, 0, stream>>>(spec, basep, ordn);
    k_tables<<<(NSPEC * HD + 255) / 256, 256, 0, stream>>>(We, Wsc1, Wup01, sc0s, h0s);
    k_compact<<<NE / 256, 256, 0, stream>>>(pos, shifts, idx_i, idx_j, cnt, act_i, act_j, actY, actF);
    k_edge1<<<512, 256, 0, stream>>>(cnt, act_i, act_j, actY, actF, spec,
                                     R10, R11, R12, R13, h0s, a0_1, a1_1);
    k_nodeAB<<<NN / 16, 256, 0, stream>>>(a0_1, a1_1, ordn, spec, Wout01, Wout11, Wp01, Wp11,
                                          Wl01, Wl11, sc0s, Wsc2, Wup02, Wup12,
                                          out, sc0b, g0, g1);
    k_edge2<<<512, 256, 0, stream>>>(cnt, act_i, act_j, actY, actF,
                                     R20, R21, R22, R23, g0, g1, a0_2, a1_2);
    k_nodeC<<<NN / 16, 256, 0, stream>>>(a0_2, a1_2, spec, Wout02, Wout12, Wp02, Wl02,
                                         sc0b, out + (size_t)NN * HD);
}

// Round 4
// 359.777 us; speedup vs baseline: 1.0070x; 1.0070x over previous
//
#include <hip/hip_runtime.h>
#include <math.h>

#define NN 10000
#define NE 256000
#define HD 128
#define PD 64
#define NBASIS 8
#define NSPEC 10
#define RHID 64
#define RCUT 5.0f
#define INV_AVG 0.0390625f   // 1/25.6 exact
#define PI_F 3.14159265358979f

__device__ __forceinline__ float silu(float x) {
    return x / (1.0f + expf(-x));
}

// ---------------- zero accumulators + counters ----------------
__global__ void k_zero(float4* acc, int* cnt, int* hist, long n4) {
    long i = (long)blockIdx.x * blockDim.x + threadIdx.x;
    if (i == 0) {
        *cnt = 0;
        for (int s = 0; s < NSPEC; s++) hist[s] = 0;
    }
    long stride = (long)gridDim.x * blockDim.x;
    float4 z = make_float4(0.f, 0.f, 0.f, 0.f);
    for (; i < n4; i += stride) acc[i] = z;
}

// ---------------- species id per node + histogram ----------------
__global__ void k_species(const float* __restrict__ na, int* __restrict__ spec, int* hist) {
    int n = blockIdx.x * 256 + threadIdx.x;
    if (n >= NN) return;
    int s = 0;
    for (int k = 0; k < NSPEC; k++)
        if (na[n * NSPEC + k] > 0.5f) s = k;
    spec[n] = s;
    atomicAdd(&hist[s], 1);
}

__global__ void k_scan(const int* __restrict__ hist, int* __restrict__ basep) {
    if (threadIdx.x == 0) {
        int acc = 0;
        for (int s = 0; s < NSPEC; s++) { basep[s] = acc; acc += hist[s]; }
    }
}

__global__ void k_scatter(const int* __restrict__ spec, int* basep, int* __restrict__ ord) {
    int n = blockIdx.x * 256 + threadIdx.x;
    if (n >= NN) return;
    int pos = atomicAdd(&basep[spec[n]], 1);
    ord[pos] = n;
}

// ---------------- per-species tables: sc0_s, h0_s ----------------
__global__ void k_tables(const float* __restrict__ We, const float* __restrict__ Wsc1,
                         const float* __restrict__ Wup01,
                         float* __restrict__ sc0s, float* __restrict__ h0s) {
    int t = blockIdx.x * 256 + threadIdx.x;
    if (t >= NSPEC * HD) return;
    int s = t / HD, h = t % HD;
    float acc1 = 0.f, acc2 = 0.f;
    for (int c = 0; c < HD; c++) {
        float fe = We[s * HD + c];
        acc1 += fe * Wsc1[(s * HD + c) * HD + h];
        acc2 += fe * Wup01[c * HD + h];
    }
    sc0s[t] = acc1;
    h0s[t] = acc2;
}

// ---------------- edge compaction: geometry + radial basis ----------------
__global__ void k_compact(const float* __restrict__ pos, const float* __restrict__ shifts,
                          const int* __restrict__ ii, const int* __restrict__ jj,
                          int* cnt, int* __restrict__ ai, int* __restrict__ aj,
                          float* __restrict__ aY, float* __restrict__ aF) {
    int e = blockIdx.x * 256 + threadIdx.x;
    if (e >= NE) return;
    int i = ii[e], j = jj[e];
    float vx = pos[i * 3 + 0] - pos[j * 3 + 0] - shifts[e * 3 + 0];
    float vy = pos[i * 3 + 1] - pos[j * 3 + 1] - shifts[e * 3 + 1];
    float vz = pos[i * 3 + 2] - pos[j * 3 + 2] - shifts[e * 3 + 2];
    float r = sqrtf(vx * vx + vy * vy + vz * vz);
    r = fmaxf(r, 1e-9f);
    if (r >= RCUT) return;   // env==0 exactly -> message exactly 0 -> skip
    int slot = atomicAdd(cnt, 1);
    ai[slot] = i; aj[slot] = j;
    float inv = 1.0f / r;
    aY[slot * 3 + 0] = vx * inv;
    aY[slot * 3 + 1] = vy * inv;
    aY[slot * 3 + 2] = vz * inv;
    float u = r * (1.0f / RCUT);
    float u5 = u * u * u * u * u;
    float env = 1.0f - 21.0f * u5 + 35.0f * u5 * u - 15.0f * u5 * u * u;
    float c0 = 0.6324555320336759f * env * inv;  // sqrt(2/RC)
    for (int b = 1; b <= NBASIS; b++)
        aF[slot * NBASIS + b - 1] = c0 * sinf((float)b * PI_F * r * (1.0f / RCUT));
}

// ---------------- layer-1 edge: 4 edges per wave, gathers hoisted ----------------
__global__ __launch_bounds__(256) void k_edge1(
    const int* __restrict__ cnt, const int* __restrict__ ai, const int* __restrict__ aj,
    const float* __restrict__ aY, const float* __restrict__ aF, const int* __restrict__ spec,
    const float* __restrict__ R0, const float* __restrict__ R1,
    const float* __restrict__ R2, const float* __restrict__ R3,
    const float* __restrict__ h0s, float* __restrict__ a0, float* __restrict__ a1) {
    int lane = threadIdx.x & 63;
    int wid = (blockIdx.x * blockDim.x + threadIdx.x) >> 6;
    int nw = (gridDim.x * blockDim.x) >> 6;
    int nact = *cnt;
    for (int base = wid * 4; base < nact; base += nw * 4) {
        int ne = nact - base; if (ne > 4) ne = 4;
        int ei[4], ej[4];
        float Y[4][3], F[4][NBASIS];
        float h0a[4], h0b[4];
        #pragma unroll
        for (int k = 0; k < 4; k++) {
            int ee = base + ((k < ne) ? k : 0);
            ei[k] = ai[ee]; ej[k] = aj[ee];
            #pragma unroll
            for (int d = 0; d < 3; d++) Y[k][d] = aY[ee * 3 + d];
            #pragma unroll
            for (int b = 0; b < NBASIS; b++) F[k][b] = aF[ee * NBASIS + b];
        }
        #pragma unroll
        for (int k = 0; k < 4; k++) {
            const float* h0 = h0s + spec[ej[k]] * HD;
            h0a[k] = h0[lane]; h0b[k] = h0[64 + lane];
        }
        float x[4];
        #pragma unroll
        for (int k = 0; k < 4; k++) {
            float acc = 0.f;
            #pragma unroll
            for (int b = 0; b < NBASIS; b++) acc += F[k][b] * R0[b * RHID + lane];
            x[k] = silu(acc);
        }
        {
            float acc[4] = {0.f, 0.f, 0.f, 0.f};
            for (int c = 0; c < RHID; c++) {
                float wv = R1[c * RHID + lane];
                #pragma unroll
                for (int k = 0; k < 4; k++) acc[k] += __shfl(x[k], c) * wv;
            }
            #pragma unroll
            for (int k = 0; k < 4; k++) x[k] = silu(acc[k]);
        }
        {
            float acc[4] = {0.f, 0.f, 0.f, 0.f};
            for (int c = 0; c < RHID; c++) {
                float wv = R2[c * RHID + lane];
                #pragma unroll
                for (int k = 0; k < 4; k++) acc[k] += __shfl(x[k], c) * wv;
            }
            #pragma unroll
            for (int k = 0; k < 4; k++) x[k] = silu(acc[k]);
        }
        float w00[4] = {0,0,0,0}, w01[4] = {0,0,0,0}, w10[4] = {0,0,0,0}, w11[4] = {0,0,0,0};
        for (int c = 0; c < RHID; c++) {
            const float* row = R3 + c * (2 * HD);
            float l0 = row[lane], l1 = row[64 + lane], l2 = row[128 + lane], l3 = row[192 + lane];
            #pragma unroll
            for (int k = 0; k < 4; k++) {
                float xc = __shfl(x[k], c);
                w00[k] += xc * l0; w01[k] += xc * l1; w10[k] += xc * l2; w11[k] += xc * l3;
            }
        }
        #pragma unroll
        for (int k = 0; k < 4; k++) {
            if (k >= ne) break;
            int i = ei[k];
            float m0a = w00[k] * h0a[k] * INV_AVG, m0b = w01[k] * h0b[k] * INV_AVG;
            float m1a = w10[k] * h0a[k] * INV_AVG, m1b = w11[k] * h0b[k] * INV_AVG;
            atomicAdd(&a0[(size_t)i * HD + lane], m0a);
            atomicAdd(&a0[(size_t)i * HD + 64 + lane], m0b);
            #pragma unroll
            for (int d = 0; d < 3; d++) {
                atomicAdd(&a1[((size_t)d * NN + i) * HD + lane], m1a * Y[k][d]);
                atomicAdd(&a1[((size_t)d * NN + i) * HD + 64 + lane], m1b * Y[k][d]);
            }
        }
    }
}

// ---------------- proj: Am = X @ W  ([NN,128]@[128,64]), y selects stream ----------------
// y=0: a0 @ W0 -> am0 ; y=1..3: a1[d] @ W1 -> am1[d]
__global__ __launch_bounds__(256) void k_proj(
    const float* __restrict__ x0buf, const float* __restrict__ x1buf,
    const float* __restrict__ W0, const float* __restrict__ W1,
    float* __restrict__ am0, float* __restrict__ am1) {
    int lane = threadIdx.x & 63;
    int w = __builtin_amdgcn_readfirstlane((int)(threadIdx.x >> 6));
    int y = blockIdx.y;
    int n0 = blockIdx.x * 16 + w * 4;
    const float* X = (y == 0) ? x0buf : (x1buf + (size_t)(y - 1) * NN * HD);
    const float* W = (y == 0) ? W0 : W1;
    float* dst = (y == 0) ? am0 : (am1 + (size_t)(y - 1) * NN * PD);
    const float* xr0 = X + (size_t)n0 * HD;
    const float* xr1 = xr0 + HD;
    const float* xr2 = xr1 + HD;
    const float* xr3 = xr2 + HD;
    float acc0 = 0.f, acc1 = 0.f, acc2 = 0.f, acc3 = 0.f;
    #pragma unroll 4
    for (int h = 0; h < HD; h++) {
        float wv = W[h * PD + lane];
        acc0 += xr0[h] * wv;
        acc1 += xr1[h] * wv;
        acc2 += xr2[h] * wv;
        acc3 += xr3[h] * wv;
    }
    dst[(size_t)(n0 + 0) * PD + lane] = acc0;
    dst[(size_t)(n0 + 1) * PD + lane] = acc1;
    dst[(size_t)(n0 + 2) * PD + lane] = acc2;
    dst[(size_t)(n0 + 3) * PD + lane] = acc3;
}

// ---------------- bout: B tensors + out-contraction, y selects stream ----------------
// y=0: B0 -> out0 = B0@Wl0 + sc0s ; y=1..3: B1[d] -> out1p[d] = B1[d]@Wl1
__global__ __launch_bounds__(256) void k_bout(
    const float* __restrict__ am0, const float* __restrict__ am1,
    const int* __restrict__ spec,
    const float* __restrict__ Wp0, const float* __restrict__ Wp1,
    const float* __restrict__ Wl0, const float* __restrict__ Wl1,
    const float* __restrict__ sc0s,
    float* __restrict__ out0, float* __restrict__ out1p) {
    __shared__ float sPack[4][PD][4];
    int lane = threadIdx.x & 63;
    int w = __builtin_amdgcn_readfirstlane((int)(threadIdx.x >> 6));
    int y = blockIdx.y;
    int n0 = blockIdx.x * 16 + w * 4;
    float B[4];
    #pragma unroll
    for (int k = 0; k < 4; k++) {
        int n = n0 + k;
        int s = spec[n];
        float A0v = am0[(size_t)n * PD + lane];
        float a1x = am1[((size_t)0 * NN + n) * PD + lane];
        float a1y = am1[((size_t)1 * NN + n) * PD + lane];
        float a1z = am1[((size_t)2 * NN + n) * PD + lane];
        float dot = a1x * a1x + a1y * a1y + a1z * a1z;
        float A02 = A0v * A0v;
        if (y == 0) {
            const float* wp = Wp0 + (size_t)(s * 5) * PD;
            B[k] = wp[lane] * A0v + wp[PD + lane] * A02 + wp[2 * PD + lane] * A02 * A0v +
                   wp[3 * PD + lane] * dot + wp[4 * PD + lane] * A0v * dot;
        } else {
            const float* wp = Wp1 + (size_t)(s * 4) * PD;
            float fac = wp[lane] + wp[PD + lane] * A0v + wp[2 * PD + lane] * A02 + wp[3 * PD + lane] * dot;
            float a1d = (y == 1) ? a1x : ((y == 2) ? a1y : a1z);
            B[k] = fac * a1d;
        }
    }
    *(float4*)&sPack[w][lane][0] = make_float4(B[0], B[1], B[2], B[3]);
    // wave-private LDS region: no barrier needed
    const float* Wl = (y == 0) ? Wl0 : Wl1;
    float oa[4] = {0, 0, 0, 0}, ob[4] = {0, 0, 0, 0};
    for (int q = 0; q < PD; q++) {
        float4 b = *(const float4*)&sPack[w][q][0];
        float wla = Wl[q * HD + lane], wlb = Wl[q * HD + 64 + lane];
        oa[0] += b.x * wla; ob[0] += b.x * wlb;
        oa[1] += b.y * wla; ob[1] += b.y * wlb;
        oa[2] += b.z * wla; ob[2] += b.z * wlb;
        oa[3] += b.w * wla; ob[3] += b.w * wlb;
    }
    if (y == 0) {
        #pragma unroll
        for (int k = 0; k < 4; k++) {
            int n = n0 + k, s = spec[n];
            out0[(size_t)n * HD + lane] = oa[k] + sc0s[s * HD + lane];
            out0[(size_t)n * HD + 64 + lane] = ob[k] + sc0s[s * HD + 64 + lane];
        }
    } else {
        float* dst = out1p + (size_t)(y - 1) * NN * HD;
        #pragma unroll
        for (int k = 0; k < 4; k++) {
            int n = n0 + k;
            dst[(size_t)n * HD + lane] = oa[k];
            dst[(size_t)n * HD + 64 + lane] = ob[k];
        }
    }
}

// ---------------- g: layer-2 feature prep, y selects stream ----------------
// y=0: sc0b = out0@Wsc2[s] ; y=1: g0 = out0@Wup02 ; y=2..4: g1[d] = out1p[d]@Wup12
__global__ __launch_bounds__(256) void k_g(
    const float* __restrict__ out0, const float* __restrict__ out1p,
    const int* __restrict__ ord, const int* __restrict__ spec,
    const float* __restrict__ Wsc2, const float* __restrict__ Wup02, const float* __restrict__ Wup12,
    float* __restrict__ sc0b, float* __restrict__ g0, float* __restrict__ g1) {
    int lane = threadIdx.x & 63;
    int w = __builtin_amdgcn_readfirstlane((int)(threadIdx.x >> 6));
    int y = blockIdx.y;
    int nb = blockIdx.x * 16 + w * 4;
    int n[4], sk[4];
    #pragma unroll
    for (int k = 0; k < 4; k++) { n[k] = ord[nb + k]; sk[k] = spec[n[k]]; }
    const float* X = (y <= 1) ? out0 : (out1p + (size_t)(y - 2) * NN * HD);
    const float* xr0 = X + (size_t)n[0] * HD;
    const float* xr1 = X + (size_t)n[1] * HD;
    const float* xr2 = X + (size_t)n[2] * HD;
    const float* xr3 = X + (size_t)n[3] * HD;
    float aa[4] = {0, 0, 0, 0}, ab[4] = {0, 0, 0, 0};
    if (y == 0) {
        bool uni = (sk[0] == sk[1]) && (sk[1] == sk[2]) && (sk[2] == sk[3]);
        if (uni) {
            const float* Wt = Wsc2 + (size_t)sk[0] * HD * HD;
            #pragma unroll 2
            for (int c = 0; c < HD; c++) {
                float wa = Wt[c * HD + lane], wb = Wt[c * HD + 64 + lane];
                aa[0] += xr0[c] * wa; ab[0] += xr0[c] * wb;
                aa[1] += xr1[c] * wa; ab[1] += xr1[c] * wb;
                aa[2] += xr2[c] * wa; ab[2] += xr2[c] * wb;
                aa[3] += xr3[c] * wa; ab[3] += xr3[c] * wb;
            }
        } else {
            #pragma unroll
            for (int k = 0; k < 4; k++) {
                const float* Wt = Wsc2 + (size_t)sk[k] * HD * HD;
                const float* xr = X + (size_t)n[k] * HD;
                float paa = 0.f, pab = 0.f;
                for (int c = 0; c < HD; c++) {
                    float xv = xr[c];
                    paa += xv * Wt[c * HD + lane];
                    pab += xv * Wt[c * HD + 64 + lane];
                }
                aa[k] = paa; ab[k] = pab;
            }
        }
        #pragma unroll
        for (int k = 0; k < 4; k++) {
            sc0b[(size_t)n[k] * HD + lane] = aa[k];
            sc0b[(size_t)n[k] * HD + 64 + lane] = ab[k];
        }
    } else {
        const float* Wt = (y == 1) ? Wup02 : Wup12;
        #pragma unroll 2
        for (int c = 0; c < HD; c++) {
            float wa = Wt[c * HD + lane], wb = Wt[c * HD + 64 + lane];
            aa[0] += xr0[c] * wa; ab[0] += xr0[c] * wb;
            aa[1] += xr1[c] * wa; ab[1] += xr1[c] * wb;
            aa[2] += xr2[c] * wa; ab[2] += xr2[c] * wb;
            aa[3] += xr3[c] * wa; ab[3] += xr3[c] * wb;
        }
        float* dst = (y == 1) ? g0 : (g1 + (size_t)(y - 2) * NN * HD);
        #pragma unroll
        for (int k = 0; k < 4; k++) {
            dst[(size_t)n[k] * HD + lane] = aa[k];
            dst[(size_t)n[k] * HD + 64 + lane] = ab[k];
        }
    }
}

// ---------------- layer-2 edge: 4 edges per wave, gathers hoisted, planar ----------------
__global__ __launch_bounds__(256) void k_edge2(
    const int* __restrict__ cnt, const int* __restrict__ ai, const int* __restrict__ aj,
    const float* __restrict__ aY, const float* __restrict__ aF,
    const float* __restrict__ R0, const float* __restrict__ R1,
    const float* __restrict__ R2, const float* __restrict__ R3,
    const float* __restrict__ g0, const float* __restrict__ g1,
    float* __restrict__ a0, float* __restrict__ a1) {
    int lane = threadIdx.x & 63;
    int wid = (blockIdx.x * blockDim.x + threadIdx.x) >> 6;
    int nw = (gridDim.x * blockDim.x) >> 6;
    int nact = *cnt;
    for (int base = wid * 4; base < nact; base += nw * 4) {
        int ne = nact - base; if (ne > 4) ne = 4;
        int ei[4], ej[4];
        float Y[4][3], F[4][NBASIS];
        float gva[4], gvb[4], g1av[4][3], g1bv[4][3];
        #pragma unroll
        for (int k = 0; k < 4; k++) {
            int ee = base + ((k < ne) ? k : 0);
            ei[k] = ai[ee]; ej[k] = aj[ee];
            #pragma unroll
            for (int d = 0; d < 3; d++) Y[k][d] = aY[ee * 3 + d];
            #pragma unroll
            for (int b = 0; b < NBASIS; b++) F[k][b] = aF[ee * NBASIS + b];
        }
        #pragma unroll
        for (int k = 0; k < 4; k++) {
            int j = ej[k];
            gva[k] = g0[(size_t)j * HD + lane];
            gvb[k] = g0[(size_t)j * HD + 64 + lane];
            #pragma unroll
            for (int d = 0; d < 3; d++) {
                g1av[k][d] = g1[((size_t)d * NN + j) * HD + lane];
                g1bv[k][d] = g1[((size_t)d * NN + j) * HD + 64 + lane];
            }
        }
        float x[4];
        #pragma unroll
        for (int k = 0; k < 4; k++) {
            float acc = 0.f;
            #pragma unroll
            for (int b = 0; b < NBASIS; b++) acc += F[k][b] * R0[b * RHID + lane];
            x[k] = silu(acc);
        }
        {
            float acc[4] = {0.f, 0.f, 0.f, 0.f};
            for (int c = 0; c < RHID; c++) {
                float wv = R1[c * RHID + lane];
                #pragma unroll
                for (int k = 0; k < 4; k++) acc[k] += __shfl(x[k], c) * wv;
            }
            #pragma unroll
            for (int k = 0; k < 4; k++) x[k] = silu(acc[k]);
        }
        {
            float acc[4] = {0.f, 0.f, 0.f, 0.f};
            for (int c = 0; c < RHID; c++) {
                float wv = R2[c * RHID + lane];
                #pragma unroll
                for (int k = 0; k < 4; k++) acc[k] += __shfl(x[k], c) * wv;
            }
            #pragma unroll
            for (int k = 0; k < 4; k++) x[k] = silu(acc[k]);
        }
        float wa[4][5] = {{0}}, wb[4][5] = {{0}};
        for (int c = 0; c < RHID; c++) {
            const float* row = R3 + c * (5 * HD);
            float la[5], lb[5];
            #pragma unroll
            for (int q = 0; q < 5; q++) { la[q] = row[q * HD + lane]; lb[q] = row[q * HD + 64 + lane]; }
            #pragma unroll
            for (int k = 0; k < 4; k++) {
                float xc = __shfl(x[k], c);
                #pragma unroll
                for (int q = 0; q < 5; q++) { wa[k][q] += xc * la[q]; wb[k][q] += xc * lb[q]; }
            }
        }
        #pragma unroll
        for (int k = 0; k < 4; k++) {
            if (k >= ne) break;
            int i = ei[k];
            float Yx = Y[k][0], Yy = Y[k][1], Yz = Y[k][2];
            float gax = g1av[k][0], gay = g1av[k][1], gaz = g1av[k][2];
            float gbx = g1bv[k][0], gby = g1bv[k][1], gbz = g1bv[k][2];
            float dota = gax * Yx + gay * Yy + gaz * Yz;
            float dotb = gbx * Yx + gby * Yy + gbz * Yz;
            float m0a = (wa[k][0] * gva[k] + wa[k][3] * dota) * INV_AVG;
            float m0b = (wb[k][0] * gvb[k] + wb[k][3] * dotb) * INV_AVG;
            float cax = gay * Yz - gaz * Yy, cay = gaz * Yx - gax * Yz, caz = gax * Yy - gay * Yx;
            float cbx = gby * Yz - gbz * Yy, cby = gbz * Yx - gbx * Yz, cbz = gbx * Yy - gby * Yx;
            float m1a[3], m1b[3];
            m1a[0] = (wa[k][1] * gva[k] * Yx + wa[k][2] * gax + wa[k][4] * cax) * INV_AVG;
            m1a[1] = (wa[k][1] * gva[k] * Yy + wa[k][2] * gay + wa[k][4] * cay) * INV_AVG;
            m1a[2] = (wa[k][1] * gva[k] * Yz + wa[k][2] * gaz + wa[k][4] * caz) * INV_AVG;
            m1b[0] = (wb[k][1] * gvb[k] * Yx + wb[k][2] * gbx + wb[k][4] * cbx) * INV_AVG;
            m1b[1] = (wb[k][1] * gvb[k] * Yy + wb[k][2] * gby + wb[k][4] * cby) * INV_AVG;
            m1b[2] = (wb[k][1] * gvb[k] * Yz + wb[k][2] * gbz + wb[k][4] * cbz) * INV_AVG;
            atomicAdd(&a0[(size_t)i * HD + lane], m0a);
            atomicAdd(&a0[(size_t)i * HD + 64 + lane], m0b);
            #pragma unroll
            for (int d = 0; d < 3; d++) {
                atomicAdd(&a1[((size_t)d * NN + i) * HD + lane], m1a[d]);
                atomicAdd(&a1[((size_t)d * NN + i) * HD + 64 + lane], m1b[d]);
            }
        }
    }
}

// ---------------- outC: B0' + final contraction (8 nodes/block, 2/wave) ----------------
__global__ __launch_bounds__(256) void k_outC(
    const float* __restrict__ am0, const float* __restrict__ am1,
    const int* __restrict__ spec, const float* __restrict__ Wp0,
    const float* __restrict__ Wl0, const float* __restrict__ sc0b,
    float* __restrict__ outb) {
    __shared__ float sPack[4][PD][2];
    int lane = threadIdx.x & 63;
    int w = __builtin_amdgcn_readfirstlane((int)(threadIdx.x >> 6));
    int n0 = blockIdx.x * 8 + w * 2;
    float B[2];
    #pragma unroll
    for (int k = 0; k < 2; k++) {
        int n = n0 + k;
        int s = spec[n];
        float A0v = am0[(size_t)n * PD + lane];
        float a1x = am1[((size_t)0 * NN + n) * PD + lane];
        float a1y = am1[((size_t)1 * NN + n) * PD + lane];
        float a1z = am1[((size_t)2 * NN + n) * PD + lane];
        float dot = a1x * a1x + a1y * a1y + a1z * a1z;
        float A02 = A0v * A0v;
        const float* wp = Wp0 + (size_t)(s * 5) * PD;
        B[k] = wp[lane] * A0v + wp[PD + lane] * A02 + wp[2 * PD + lane] * A02 * A0v +
               wp[3 * PD + lane] * dot + wp[4 * PD + lane] * A0v * dot;
    }
    *(float2*)&sPack[w][lane][0] = make_float2(B[0], B[1]);
    float oa[2] = {0, 0}, ob[2] = {0, 0};
    for (int q = 0; q < PD; q++) {
        float2 b = *(const float2*)&sPack[w][q][0];
        float wla = Wl0[q * HD + lane], wlb = Wl0[q * HD + 64 + lane];
        oa[0] += b.x * wla; ob[0] += b.x * wlb;
        oa[1] += b.y * wla; ob[1] += b.y * wlb;
    }
    #pragma unroll
    for (int k = 0; k < 2; k++) {
        int n = n0 + k;
        outb[(size_t)n * HD + lane] = oa[k] + sc0b[(size_t)n * HD + lane];
        outb[(size_t)n * HD + 64 + lane] = ob[k] + sc0b[(size_t)n * HD + 64 + lane];
    }
}

extern "C" void kernel_launch(void* const* d_in, const int* in_sizes, int n_in,
                              void* d_out, int out_size, void* d_ws, size_t ws_size,
                              hipStream_t stream) {
    const float* pos    = (const float*)d_in[0];
    const float* shifts = (const float*)d_in[1];
    const float* na     = (const float*)d_in[2];
    const float* We     = (const float*)d_in[3];
    const float* Wsc1   = (const float*)d_in[4];
    const float* Wup01  = (const float*)d_in[5];
    const float* R10    = (const float*)d_in[6];
    const float* R11    = (const float*)d_in[7];
    const float* R12    = (const float*)d_in[8];
    const float* R13    = (const float*)d_in[9];
    const float* Wout01 = (const float*)d_in[10];
    const float* Wout11 = (const float*)d_in[11];
    const float* Wp01   = (const float*)d_in[12];
    const float* Wp11   = (const float*)d_in[13];
    const float* Wl01   = (const float*)d_in[14];
    const float* Wl11   = (const float*)d_in[15];
    const float* Wsc2   = (const float*)d_in[16];
    const float* Wup02  = (const float*)d_in[17];
    const float* Wup12  = (const float*)d_in[18];
    const float* R20    = (const float*)d_in[19];
    const float* R21    = (const float*)d_in[20];
    const float* R22    = (const float*)d_in[21];
    const float* R23    = (const float*)d_in[22];
    const float* Wout02 = (const float*)d_in[23];
    const float* Wout12 = (const float*)d_in[24];
    const float* Wp02   = (const float*)d_in[25];
    const float* Wl02   = (const float*)d_in[26];
    const int*   idx_i  = (const int*)d_in[27];
    const int*   idx_j  = (const int*)d_in[28];
    float* out = (float*)d_out;

    char* ws = (char*)d_ws;
    size_t off = 0;
    auto alloc = [&](size_t bytes) -> char* {
        char* pp = ws + off;
        off += (bytes + 255) & ~(size_t)255;
        return pp;
    };
    int*   cnt   = (int*)alloc(4);
    int*   hist  = (int*)alloc(NSPEC * 4);
    int*   basep = (int*)alloc(NSPEC * 4);
    // the next 4 arrays must stay contiguous for k_zero (8*NN*HD floats total)
    float* a0_1  = (float*)alloc((size_t)NN * HD * 4);
    float* a1_1  = (float*)alloc((size_t)NN * HD * 3 * 4);   // planar [3][NN][HD]; reused as out1p
    float* a0_2  = (float*)alloc((size_t)NN * HD * 4);
    float* a1_2  = (float*)alloc((size_t)NN * HD * 3 * 4);   // planar
    int*   act_i = (int*)alloc((size_t)NE * 4);
    int*   act_j = (int*)alloc((size_t)NE * 4);
    float* actY  = (float*)alloc((size_t)NE * 3 * 4);
    float* actF  = (float*)alloc((size_t)NE * NBASIS * 4);
    int*   spec  = (int*)alloc((size_t)NN * 4);
    int*   ordn  = (int*)alloc((size_t)NN * 4);
    float* sc0s  = (float*)alloc((size_t)NSPEC * HD * 4);
    float* h0s   = (float*)alloc((size_t)NSPEC * HD * 4);
    float* sc0b  = (float*)alloc((size_t)NN * HD * 4);
    float* g0    = (float*)alloc((size_t)NN * HD * 4);
    float* g1    = (float*)alloc((size_t)NN * HD * 3 * 4);   // planar
    float* am0   = (float*)alloc((size_t)NN * PD * 4);       // A0  [NN][64]
    float* am1   = (float*)alloc((size_t)NN * PD * 3 * 4);   // A1  [3][NN][64]
    float* out1p = a1_1;   // reuse: a1_1 is dead after k_proj(layer1) reads it

    long n4 = (long)NN * HD * 8 / 4;
    k_zero<<<2048, 256, 0, stream>>>((float4*)a0_1, cnt, hist, n4);
    k_species<<<(NN + 255) / 256, 256, 0, stream>>>(na, spec, hist);
    k_scan<<<1, 64, 0, stream>>>(hist, basep);
    k_scatter<<<(NN + 255) / 256, 256, 0, stream>>>(spec, basep, ordn);
    k_tables<<<(NSPEC * HD + 255) / 256, 256, 0, stream>>>(We, Wsc1, Wup01, sc0s, h0s);
    k_compact<<<NE / 256, 256, 0, stream>>>(pos, shifts, idx_i, idx_j, cnt, act_i, act_j, actY, actF);
    k_edge1<<<512, 256, 0, stream>>>(cnt, act_i, act_j, actY, actF, spec,
                                     R10, R11, R12, R13, h0s, a0_1, a1_1);
    k_proj<<<dim3(NN / 16, 4), 256, 0, stream>>>(a0_1, a1_1, Wout01, Wout11, am0, am1);
    k_bout<<<dim3(NN / 16, 4), 256, 0, stream>>>(am0, am1, spec, Wp01, Wp11, Wl01, Wl11,
                                                 sc0s, out, out1p);
    k_g<<<dim3(NN / 16, 5), 256, 0, stream>>>(out, out1p, ordn, spec, Wsc2, Wup02, Wup12,
                                              sc0b, g0, g1);
    k_edge2<<<512, 256, 0, stream>>>(cnt, act_i, act_j, actY, actF,
                                     R20, R21, R22, R23, g0, g1, a0_2, a1_2);
    k_proj<<<dim3(NN / 16, 4), 256, 0, stream>>>(a0_2, a1_2, Wout02, Wout12, am0, am1);
    k_outC<<<NN / 8, 256, 0, stream>>>(am0, am1, spec, Wp02, Wl02, sc0b, out + (size_t)NN * HD);
}